// Round 3
// baseline (397.326 us; speedup 1.0000x reference)
//
#include <hip/hip_runtime.h>

// HashGrid2D: out[i, :] = table[hash(positions[i]), :]
// hash = ((floor(x)*73856093) ^ (floor(y)*19349663)) & (2^19 - 1)
//
// R5 post-mortem: two-phase compaction made gathers dense + L2-resident but
// output stores became a random permutation -> 2M random 128B HBM WRITES =
// the same DRAM-activate wall as R0's random reads (~0.9 TB/s effective).
// Conservation of randomness: the r-order<->h-order permutation must cross
// some tier at 128B granularity. R6 puts that tier in LDS/L2:
//   - block owns a contiguous 512-row out chunk, assembled in LDS;
//   - s-loop over 16 x 4MB hash slices: block-compact in-slice rows to an
//     LDS list (parity dbuf, 2 syncs/iter), dense per-row gathers from the
//     slice window (co-resident blocks march s in rough lockstep -> slice
//     stays in each XCD's L2; skew absorbed by L3 which holds all 64MB);
//   - final phase streams the 64KB chunk to out SEQUENTIALLY (nt stores).
// HBM traffic: pos 16MB + table ~64MB + out 256MB, all streaming-friendly.
// LDS row stride 144B (16B-aligned, spreads banks). 512 thr + ~75KB LDS
// -> 2 blocks/CU; the two blocks' phases overlap to hide gather latency.

#define HASH_MASK ((1u << 19) - 1u)
#define SLICE_SHIFT 15   // 16 slices x 32K buckets = 4MB of table each
#define NSLICE 16
#define BLOCK 512
#define CHUNK 512        // rows per block, 1 row/thread
#define CAP 128          // per-slice list capacity: mean 32, sigma 5.5 -> 17s
#define RSTRIDE 9        // LDS row stride in float4 (144B)

typedef float vfloat2 __attribute__((ext_vector_type(2)));
typedef float vfloat4 __attribute__((ext_vector_type(4)));

__global__ __launch_bounds__(BLOCK) void HashGrid2D_37383395344981_kernel(
    const vfloat2* __restrict__ pos,
    const vfloat4* __restrict__ table,   // HASH_SIZE x 8 vfloat4
    vfloat4* __restrict__ out,           // N x 8 vfloat4
    int n)
{
    __shared__ vfloat4 buf[CHUNK * RSTRIDE];
    __shared__ unsigned list[2][CAP];
    __shared__ unsigned cnt[2];

    const int tid = threadIdx.x;
    const int r0 = blockIdx.x * CHUNK;
    const int r = r0 + tid;

    // One position per thread, hash kept in a register for all 16 passes.
    unsigned h = 0xFFFFFFFFu;                 // sentinel: never matches a slice
    if (r < n) {
        vfloat2 p = __builtin_nontemporal_load(&pos[r]);
        unsigned ix = (unsigned)(int)floorf(p.x);
        unsigned iy = (unsigned)(int)floorf(p.y);
        h = ((ix * 73856093u) ^ (iy * 19349663u)) & HASH_MASK;
    }

    if (tid < 2) cnt[tid] = 0u;
    __syncthreads();

    for (unsigned s = 0; s < NSLICE; ++s) {
        const unsigned b = s & 1u;

        // PUSH: compact this slice's rows into the parity-b list.
        if ((h >> SLICE_SHIFT) == s) {
            unsigned idx = atomicAdd(&cnt[b], 1u);
            if (idx < CAP) {
                list[b][idx] = (h << 9) | (unsigned)tid;  // 19b hash | 9b row
            } else {
                // ~impossible overflow: gather own row directly (row tid is
                // exclusively ours; read only after the final barrier).
                const vfloat4* trow = table + (size_t)h * 8;
                vfloat4* lrow = buf + (size_t)tid * RSTRIDE;
#pragma unroll
                for (int c = 0; c < 8; ++c) lrow[c] = trow[c];
            }
        }
        __syncthreads();

        // GATHER: dense, one thread per listed row, 8 outstanding 16B loads
        // from the L2-resident 4MB slice window.
        if (tid == 0) cnt[b ^ 1u] = 0u;       // reset for iter s+1 (safe here)
        unsigned m = cnt[b]; if (m > CAP) m = CAP;
        for (unsigned i = tid; i < m; i += BLOCK) {
            unsigned e = list[b][i];
            unsigned hh = e >> 9;
            unsigned lr = e & 511u;
            const vfloat4* trow = table + (size_t)hh * 8;
            vfloat4 v0 = trow[0], v1 = trow[1], v2 = trow[2], v3 = trow[3];
            vfloat4 v4 = trow[4], v5 = trow[5], v6 = trow[6], v7 = trow[7];
            vfloat4* lrow = buf + (size_t)lr * RSTRIDE;
            lrow[0] = v0; lrow[1] = v1; lrow[2] = v2; lrow[3] = v3;
            lrow[4] = v4; lrow[5] = v5; lrow[6] = v6; lrow[7] = v7;
        }
        __syncthreads();
    }

    // STREAM: LDS chunk -> out, perfectly sequential nt stores.
    int nrow = n - r0; if (nrow > CHUNK) nrow = CHUNK;
    int nf4 = nrow * 8;
    vfloat4* obase = out + (size_t)r0 * 8;
    for (int i = tid; i < nf4; i += BLOCK) {
        int row = i >> 3, c = i & 7;
        __builtin_nontemporal_store(buf[(size_t)row * RSTRIDE + c], &obase[i]);
    }
}

extern "C" void kernel_launch(void* const* d_in, const int* in_sizes, int n_in,
                              void* d_out, int out_size, void* d_ws, size_t ws_size,
                              hipStream_t stream) {
    const vfloat2* pos   = (const vfloat2*)d_in[0];
    const vfloat4* table = (const vfloat4*)d_in[1];
    vfloat4* out = (vfloat4*)d_out;

    int n = in_sizes[0] / 2;
    int grid = (n + CHUNK - 1) / CHUNK;

    HashGrid2D_37383395344981_kernel<<<grid, BLOCK, 0, stream>>>(pos, table, out, n);
}

// Round 4
// 335.827 us; speedup vs baseline: 1.1831x; 1.1831x over previous
//
#include <hip/hip_runtime.h>

// HashGrid2D: out[i, :] = table[hash(positions[i]), :]
// hash = ((floor(x)*73856093) ^ (floor(y)*19349663)) & (2^19 - 1)
//
// R6 post-mortem: slice-phasing worked (FETCH 126MB ~= pos16+table64) but
// the kernel REGRESSED vs the simple gather (168us vs ~103us): 32 barriers
// per block and a gather phase where only 32/512 threads were active made
// it serialization-bound (VALUBusy 9.5%, occ 42%, 2.3 TB/s).
// R7: same dataflow, zero per-slice barriers.
//   - one-shot exact bucket sort of the block's 512 rows by hash-slice:
//     counts -> exclusive prefix -> scatter (h<<9|row) into perm[512].
//     4 barriers total, no capacity/overflow paths.
//   - barrier-free gather: 8 lanes/row, 16 rounds x 64 rows in perm
//     (slice-sorted) order. All 512 threads active; rounds pipeline
//     (unroll 8 -> many 16B loads in flight); request stream still
//     slice-ordered so co-resident blocks keep a ~4MB window hot in L2.
//   - stream the assembled 64KB chunk to out sequentially (nt stores).
// LDS row stride 144B: each 128B row spans all 32 banks exactly once ->
// wave-level LDS writes/reads are bandwidth-minimal.

#define HASH_MASK ((1u << 19) - 1u)
#define SLICE_SHIFT 15   // 16 slices x 32K buckets = 4MB of table each
#define NSLICE 16
#define BLOCK 512
#define CHUNK 512        // rows per block, 1 row/thread
#define RSTRIDE 9        // LDS row stride in float4 (144B)

typedef float vfloat2 __attribute__((ext_vector_type(2)));
typedef float vfloat4 __attribute__((ext_vector_type(4)));

__global__ __launch_bounds__(BLOCK) void HashGrid2D_37383395344981_kernel(
    const vfloat2* __restrict__ pos,
    const vfloat4* __restrict__ table,   // HASH_SIZE x 8 vfloat4
    vfloat4* __restrict__ out,           // N x 8 vfloat4
    int n)
{
    __shared__ vfloat4 buf[CHUNK * RSTRIDE];   // 72 KB
    __shared__ unsigned cnt[NSLICE];
    __shared__ unsigned sbase[NSLICE];
    __shared__ unsigned perm[CHUNK];           // 2 KB

    const int tid = threadIdx.x;
    const int r0 = blockIdx.x * CHUNK;
    const int r = r0 + tid;
    const bool valid = (r < n);

    if (tid < NSLICE) cnt[tid] = 0u;
    __syncthreads();

    // Hash own row; rank within its slice via LDS atomic.
    unsigned h = 0u, rank = 0u;
    if (valid) {
        vfloat2 p = __builtin_nontemporal_load(&pos[r]);
        unsigned ix = (unsigned)(int)floorf(p.x);
        unsigned iy = (unsigned)(int)floorf(p.y);
        h = ((ix * 73856093u) ^ (iy * 19349663u)) & HASH_MASK;
        rank = atomicAdd(&cnt[h >> SLICE_SHIFT], 1u);
    }
    __syncthreads();

    if (tid == 0) {            // exclusive prefix over 16 counts
        unsigned acc = 0u;
#pragma unroll
        for (int s = 0; s < NSLICE; ++s) { sbase[s] = acc; acc += cnt[s]; }
    }
    __syncthreads();

    if (valid) perm[sbase[h >> SLICE_SHIFT] + rank] = (h << 9) | (unsigned)tid;
    __syncthreads();

    // Barrier-free gather in slice-sorted order: 8 lanes/row, 16 rounds.
    const int nrow = (n - r0 < CHUNK) ? (n - r0) : CHUNK;
    const int c = tid & 7;
    const int ri = tid >> 3;                   // row-slot within a round
#pragma unroll 8
    for (int j = 0; j < CHUNK / 64; ++j) {
        int i = ri + 64 * j;
        if (i < nrow) {
            unsigned e = perm[i];
            unsigned hh = e >> 9;
            unsigned lr = e & 511u;
            vfloat4 v = table[(size_t)hh * 8 + c];     // L2-hot 4MB window
            buf[(size_t)lr * RSTRIDE + c] = v;
        }
    }
    __syncthreads();

    // Stream the assembled chunk to out: perfectly sequential nt stores.
    const int nf4 = nrow * 8;
    vfloat4* obase = out + (size_t)r0 * 8;
    for (int i = tid; i < nf4; i += BLOCK) {
        int row = i >> 3, cc = i & 7;
        __builtin_nontemporal_store(buf[(size_t)row * RSTRIDE + cc], &obase[i]);
    }
}

extern "C" void kernel_launch(void* const* d_in, const int* in_sizes, int n_in,
                              void* d_out, int out_size, void* d_ws, size_t ws_size,
                              hipStream_t stream) {
    const vfloat2* pos   = (const vfloat2*)d_in[0];
    const vfloat4* table = (const vfloat4*)d_in[1];
    vfloat4* out = (vfloat4*)d_out;

    int n = in_sizes[0] / 2;
    int grid = (n + CHUNK - 1) / CHUNK;

    HashGrid2D_37383395344981_kernel<<<grid, BLOCK, 0, stream>>>(pos, table, out, n);
}

// Round 5
// 333.032 us; speedup vs baseline: 1.1931x; 1.0084x over previous
//
#include <hip/hip_runtime.h>

// HashGrid2D: out[i, :] = table[hash(positions[i]), :]
// hash = ((floor(x)*73856093) ^ (floor(y)*19349663)) & (2^19 - 1)
//
// R7 post-mortem: LDS-assembled chunks + slice-sorted gather == R0 naive
// time (~105us kernel). Slice-ordering won back what the LDS round-trip
// + sort->gather->barrier->store serial chain (2 blocks/CU at 72KB LDS)
// cost. The permutation tier doesn't need LDS at all:
// R8: sort stays, staging goes.
//   - R7's 4-barrier exact bucket sort -> perm[512] (slice-ordered).
//   - gather loop stores DIRECTLY to the block's contiguous 64KB out
//     window: perm-order writes are random only within 64KB -> fully
//     absorbed/reordered by L2 (full 128B lines, write-once). R5's wall
//     was randomness across 256MB, not randomness per se.
//   - cached stores (L2 should buffer them); nt only on pos reads.
//   - LDS 75KB -> 2.2KB, tiny VGPR -> 4 blocks/CU, 32/32 waves; no
//     store phase, no final barrier; 8x-unrolled free-running gather.
// Read side keeps the proven slice-phase locality (R6: FETCH 126MB).

#define HASH_MASK ((1u << 19) - 1u)
#define SLICE_SHIFT 15   // 16 slices x 32K buckets = 4MB of table each
#define NSLICE 16
#define BLOCK 512
#define CHUNK 512        // rows per block, 1 row/thread

typedef float vfloat2 __attribute__((ext_vector_type(2)));
typedef float vfloat4 __attribute__((ext_vector_type(4)));

__global__ __launch_bounds__(BLOCK) void HashGrid2D_37383395344981_kernel(
    const vfloat2* __restrict__ pos,
    const vfloat4* __restrict__ table,   // HASH_SIZE x 8 vfloat4
    vfloat4* __restrict__ out,           // N x 8 vfloat4
    int n)
{
    __shared__ unsigned cnt[NSLICE];
    __shared__ unsigned sbase[NSLICE];
    __shared__ unsigned perm[CHUNK];

    const int tid = threadIdx.x;
    const int r0 = blockIdx.x * CHUNK;
    const int r = r0 + tid;
    const bool valid = (r < n);

    if (tid < NSLICE) cnt[tid] = 0u;
    __syncthreads();

    // Hash own row; rank within its slice via LDS atomic.
    unsigned h = 0u, rank = 0u;
    if (valid) {
        vfloat2 p = __builtin_nontemporal_load(&pos[r]);
        unsigned ix = (unsigned)(int)floorf(p.x);
        unsigned iy = (unsigned)(int)floorf(p.y);
        h = ((ix * 73856093u) ^ (iy * 19349663u)) & HASH_MASK;
        rank = atomicAdd(&cnt[h >> SLICE_SHIFT], 1u);
    }
    __syncthreads();

    if (tid == 0) {            // exclusive prefix over 16 counts
        unsigned acc = 0u;
#pragma unroll
        for (int s = 0; s < NSLICE; ++s) { sbase[s] = acc; acc += cnt[s]; }
    }
    __syncthreads();

    if (valid) perm[sbase[h >> SLICE_SHIFT] + rank] = (h << 9) | (unsigned)tid;
    __syncthreads();

    // Slice-ordered gather -> direct store into the block's 64KB window.
    // 8 lanes/row; each group's store is one full 128B line; random only
    // within the window -> L2 absorbs and drains near-sequentially.
    const int nrow = (n - r0 < CHUNK) ? (n - r0) : CHUNK;
    const int c = tid & 7;
    const int ri = tid >> 3;                   // row-slot within a round
    vfloat4* obase = out + (size_t)r0 * 8;
#pragma unroll 8
    for (int j = 0; j < CHUNK / 64; ++j) {
        int i = ri + 64 * j;
        if (i < nrow) {
            unsigned e = perm[i];
            unsigned hh = e >> 9;
            unsigned lr = e & 511u;
            vfloat4 v = table[(size_t)hh * 8 + c];     // L2-hot slice window
            obase[(size_t)lr * 8 + c] = v;
        }
    }
}

extern "C" void kernel_launch(void* const* d_in, const int* in_sizes, int n_in,
                              void* d_out, int out_size, void* d_ws, size_t ws_size,
                              hipStream_t stream) {
    const vfloat2* pos   = (const vfloat2*)d_in[0];
    const vfloat4* table = (const vfloat4*)d_in[1];
    vfloat4* out = (vfloat4*)d_out;

    int n = in_sizes[0] / 2;
    int grid = (n + CHUNK - 1) / CHUNK;

    HashGrid2D_37383395344981_kernel<<<grid, BLOCK, 0, stream>>>(pos, table, out, n);
}